// Round 1
// baseline (94.339 us; speedup 1.0000x reference)
//
#include <hip/hip_runtime.h>

// Dual quantized EMA scan, chunked with redundant warmup.
// State kept in scaled domain Y = y * 2^23 so the 24-bit quantize is a single
// v_rndne. alpha^256 ~ 2e-6 makes a 256-step warmup indistinguishable from the
// true prefix (error ~2.4e-7 << 2.43e-3 threshold). Clips dropped: |signals| < 1.

constexpr int T = 8192;
constexpr int C = 256;
constexpr int S = 1024;     // chunk length
constexpr int W = 256;      // warmup length
constexpr int U = 16;       // rows per load/compute group
constexpr int NCHUNK = T / S;   // 8
constexpr int CQ = C / 64;      // 4 wave-sized c-quarters

constexpr float ALPHA = 0.95f;

__device__ __forceinline__ void load_group(const float* __restrict__ xq,
                                           const float* __restrict__ yq,
                                           float* xv, float* yv) {
#pragma unroll
  for (int i = 0; i < U; ++i) {
    xv[i] = xq[(size_t)i * C];
    yv[i] = yq[(size_t)i * C];
  }
}

template <bool STORE>
__device__ __forceinline__ void proc_group(float& Y0, float& Y1,
                                           const float* xv, const float* yv,
                                           float* __restrict__ oq) {
  const float K   = (1.0f - ALPHA) * 8388608.0f;  // (1-a) * 2^23
  const float C8  = 1.0f / 256.0f;                // 2^23 -> 2^15 domain
  const float I16 = 1.0f / 32768.0f;
#pragma unroll
  for (int i = 0; i < U; ++i) {
    Y0 = rintf(fmaf(ALPHA, Y0, K * xv[i]));   // 24-bit quantized EMA (scaled)
    Y1 = rintf(fmaf(ALPHA, Y1, K * yv[i]));
    if (STORE)
      oq[(size_t)i * C] = (rintf(Y0 * C8) + rintf(Y1 * C8)) * I16;
  }
}

template <bool WARM>
__device__ __forceinline__ void run_chunk(const float* __restrict__ xp,
                                          const float* __restrict__ yp,
                                          float* __restrict__ op) {
  constexpr int WG = WARM ? (W / U) : 0;  // 16 or 0 warmup groups
  constexpr int NG = WG + S / U;          // total groups: 80 or 64
  float xa[U], ya[U], xb[U], yb[U];
  float Y0 = 0.0f, Y1 = 0.0f;

  load_group(xp, yp, xa, ya);

  if (WARM) {
#pragma unroll 1
    for (int g = 0; g < WG; g += 2) {
      load_group(xp + (size_t)(g + 1) * U * C, yp + (size_t)(g + 1) * U * C, xb, yb);
      proc_group<false>(Y0, Y1, xa, ya, nullptr);
      load_group(xp + (size_t)(g + 2) * U * C, yp + (size_t)(g + 2) * U * C, xa, ya);
      proc_group<false>(Y0, Y1, xb, yb, nullptr);
    }
  }

#pragma unroll 1
  for (int g = WG; g < NG; g += 2) {
    load_group(xp + (size_t)(g + 1) * U * C, yp + (size_t)(g + 1) * U * C, xb, yb);
    proc_group<true>(Y0, Y1, xa, ya, op + (size_t)(g - WG) * U * C);
    if (g + 2 < NG)
      load_group(xp + (size_t)(g + 2) * U * C, yp + (size_t)(g + 2) * U * C, xa, ya);
    proc_group<true>(Y0, Y1, xb, yb, op + (size_t)(g + 1 - WG) * U * C);
  }
}

__global__ __launch_bounds__(64) void I24DualEMA_kernel(const float* __restrict__ x,
                                                        const float* __restrict__ y,
                                                        float* __restrict__ out) {
  const int lane  = threadIdx.x;             // 0..63 -> c within quarter
  const int bid   = blockIdx.x;
  const int cq    = bid & (CQ - 1);
  const int chunk = (bid >> 2) & (NCHUNK - 1);
  const int b     = bid >> 5;
  const int c     = (cq << 6) | lane;
  const long t0   = (long)chunk * S;

  if (chunk == 0) {
    const size_t base = (size_t)b * T * C + c;
    run_chunk<false>(x + base, y + base, out + base);
  } else {
    const size_t baseIn  = ((size_t)b * T + (t0 - W)) * C + c;
    const size_t baseOut = ((size_t)b * T + t0) * C + c;
    run_chunk<true>(x + baseIn, y + baseIn, out + baseOut);
  }
}

extern "C" void kernel_launch(void* const* d_in, const int* in_sizes, int n_in,
                              void* d_out, int out_size, void* d_ws, size_t ws_size,
                              hipStream_t stream) {
  const float* x = (const float*)d_in[0];
  const float* y = (const float*)d_in[1];
  float* out = (float*)d_out;
  const int B = in_sizes[0] / (T * C);         // 16
  const int nblocks = B * NCHUNK * CQ;         // 512
  I24DualEMA_kernel<<<dim3(nblocks), dim3(64), 0, stream>>>(x, y, out);
}